// Round 4
// baseline (169.121 us; speedup 1.0000x reference)
//
#include <hip/hip_runtime.h>
#include <hip/hip_bf16.h>
#include <math.h>

typedef _Float16 half8 __attribute__((ext_vector_type(8)));
typedef _Float16 half4 __attribute__((ext_vector_type(4)));
typedef float f32x4 __attribute__((ext_vector_type(4)));

#define BATCH 100
#define CH    512
#define HWP   256
#define SAMP  (CH * HWP)   // 131072 elems per sample

// ---- async global->LDS 16B (wave-uniform LDS base + lane*16) ----
__device__ __forceinline__ void async16(const void* g, void* l) {
  __builtin_amdgcn_global_load_lds(
      (const __attribute__((address_space(1))) unsigned int*)g,
      (__attribute__((address_space(3))) unsigned int*)l, 16, 0, 0);
}

// ---- K0: transpose + fp32->fp16:  x[b][c][p] -> xh[b][p][c]
// 64c x 64p tile per block; LDS fp32 [64][69] (pad 5 -> max 2-way alias = free).
// Blocks >= 3200: W fp32->fp16 conversion; block 3200 also zeroes denom
// (replaces the hipMemsetAsync dispatch).
__global__ __launch_bounds__(256) void k_txpose(const float* __restrict__ x,
                                               _Float16* __restrict__ xh,
                                               const float* __restrict__ W,
                                               _Float16* __restrict__ Wh,
                                               float* __restrict__ denom) {
  __shared__ float tb[64][69];
  int bid  = blockIdx.x;
  if (bid >= 3200) {                 // W conversion tail: 256 blocks
    int base = (bid - 3200) * 1024 + threadIdx.x;
#pragma unroll
    for (int j = 0; j < 4; j++) Wh[base + j * 256] = (_Float16)W[base + j * 256];
    if (bid == 3200 && threadIdx.x < 128) denom[threadIdx.x] = 0.0f;
    return;
  }
  int b    = bid >> 5;          // 32 tiles per batch
  int tile = bid & 31;
  int c0 = (tile >> 2) << 6;    // 8 c-tiles of 64
  int p0 = (tile & 3) << 6;     // 4 p-tiles of 64
  int t = threadIdx.x;
  const float* xb = x + (size_t)b * SAMP;
#pragma unroll
  for (int it = 0; it < 4; it++) {
    int ch = it * 256 + t;
    int c  = ch >> 4;           // 0..63
    int pc = (ch & 15) << 2;    // 0..60
    float4 v = *(const float4*)(xb + (size_t)(c0 + c) * HWP + p0 + pc);
    tb[c][pc] = v.x; tb[c][pc + 1] = v.y; tb[c][pc + 2] = v.z; tb[c][pc + 3] = v.w;
  }
  __syncthreads();
  _Float16* xhb = xh + (size_t)b * SAMP;
#pragma unroll
  for (int it = 0; it < 2; it++) {
    int ch = it * 256 + t;
    int p  = ch >> 3;           // 0..63
    int ck = (ch & 7) << 3;     // 0..56
    half8 h;
#pragma unroll
    for (int j = 0; j < 8; j++) h[j] = (_Float16)tb[ck + j][p];
    *(half8*)(xhb + (size_t)(p0 + p) * CH + c0 + ck) = h;
  }
}

// ---- K1: batched GEMM + fused exp + denom partial + u = x*e (fp16) store.
// R1 core (best measured variant): runtime-q double-buffer, unswizzled frag
// reads (conflicts measured free), XCD swizzle (FETCH 57->17 MB).
// New: LDS cut to exactly 32 KB (epilogue tile XOR-swizzled [128][128] halfs,
// wave-level atomicAdd instead of cross-wave LDS reduce) -> 5 blocks/CU (was 4).
__global__ __launch_bounds__(256, 5) void k_gemm(const _Float16* __restrict__ Wh,
                                                 const _Float16* __restrict__ xh,
                                                 const float* __restrict__ bias,
                                                 _Float16* __restrict__ u,
                                                 float* __restrict__ denom) {
  __shared__ __align__(16) _Float16 smem[16384];   // 32768 B exactly
  int bid = blockIdx.x;
  // bijective XCD swizzle (800 % 8 == 0): 8 subtiles of a batch share one XCD L2
  int w     = (bid & 7) * 100 + (bid >> 3);
  int batch = w >> 3;
  int sub   = w & 7;
  int ot = sub & 3, pt = sub >> 2;     // o-tile fastest
  int o0 = ot * 128, p0 = pt * 128;
  const _Float16* Bg = xh + (size_t)batch * SAMP;   // [p][c] 256x512

  int t  = threadIdx.x;
  int wv = t >> 6, ln = t & 63;
  int qd = ln >> 4, r = ln & 15;
  int wm0 = (wv >> 1) * 64, wn0 = (wv & 1) * 64;

  auto stage = [&](int q, int kk) {
    _Float16* As = smem + q * 8192;   // 128x32
    _Float16* Bs = As + 4096;         // 128x32
#pragma unroll
    for (int it = 0; it < 2; it++) {
      int ch  = it * 256 + t;         // 0..511 chunks of 16B
      int row = ch >> 2;              // 0..127
      int qc  = ch & 3;               // 4 chunks per 64B row
      char* la = (char*)As + (size_t)(it * 256 + wv * 64) * 16;   // wave-uniform
      char* lb = (char*)Bs + (size_t)(it * 256 + wv * 64) * 16;
      async16((const char*)(Wh + (size_t)(o0 + row) * 512 + kk + qc * 8), la);
      async16((const char*)(Bg + (size_t)(p0 + row) * 512 + kk + qc * 8), lb);
    }
  };

  f32x4 acc[4][4] = {};
  stage(0, 0);
  __syncthreads();                    // drain prologue stage

  for (int ks = 0; ks < 16; ks++) {
    int q = ks & 1;
    if (ks < 15) stage(q ^ 1, (ks + 1) * 32);   // prefetch next K-step
    const _Float16* As = smem + q * 8192;
    const _Float16* Bs = As + 4096;
    half8 af[4], bf[4];
#pragma unroll
    for (int i = 0; i < 4; i++)
      af[i] = *(const half8*)(As + (wm0 + i * 16 + r) * 32 + qd * 8);
#pragma unroll
    for (int j = 0; j < 4; j++)
      bf[j] = *(const half8*)(Bs + (wn0 + j * 16 + r) * 32 + qd * 8);
#pragma unroll
    for (int i = 0; i < 4; i++)
#pragma unroll
      for (int j = 0; j < 4; j++)
        acc[i][j] = __builtin_amdgcn_mfma_f32_16x16x32_f16(af[i], bf[j], acc[i][j], 0, 0, 0);
    __syncthreads();                  // one barrier/step
  }

  // ---- epilogue: restage x-tile (xh [p][c] slice c=o0..o0+127) into 32-KB
  // XOR-swizzled LDS tile: column-octet stored at (ck ^ (p&7)).
#pragma unroll
  for (int it = 0; it < 8; it++) {
    int ch = it * 256 + t;        // 0..2047 half8-chunks
    int p  = ch >> 4;             // 0..127
    int ck = ch & 15;             // column octet
    half8 v = *(const half8*)(Bg + (size_t)(p0 + p) * CH + o0 + ck * 8);
    *(half8*)(smem + p * 128 + ((ck ^ (p & 7)) << 3)) = v;
  }
  __syncthreads();

  _Float16* outb = u + (size_t)batch * SAMP;    // [o][p]
  float lsum = 0.f;
#pragma unroll
  for (int i = 0; i < 4; i++) {
#pragma unroll
    for (int rg = 0; rg < 4; rg++) {
      int ol = wm0 + i * 16 + qd * 4 + rg;      // local o (== mask channel)
      float bv = bias[o0 + ol];
      int lo = ol >> 3, wo = ol & 7;
#pragma unroll
      for (int j = 0; j < 4; j++) {
        int pl = wn0 + j * 16 + r;              // local p
        float ev = __expf(acc[i][j][rg] + bv);
        lsum += ev;
        float xv = (float)smem[pl * 128 + ((lo ^ (pl & 7)) << 3) + wo];
        outb[(size_t)(o0 + ol) * HWP + p0 + pl] = (_Float16)(xv * ev);
      }
    }
  }
#pragma unroll
  for (int off = 32; off; off >>= 1) lsum += __shfl_down(lsum, off, 64);
  if (ln == 0) atomicAdd(&denom[batch], lsum);   // 4 atomics/block
}

// ---- K3: prototypes s[m][c] = (1/1280) * sum_j invd_j * sum_p u ----
__global__ __launch_bounds__(256) void k_proto(const _Float16* __restrict__ u,
                                              const float* __restrict__ denom,
                                              float* __restrict__ sproto) {
  int c = blockIdx.x;
  int t = threadIdx.x;                 // position p
  int wv = t >> 6;
  float accm[5];
#pragma unroll
  for (int m = 0; m < 5; m++) {
    float acc = 0.f;
#pragma unroll
    for (int j = 0; j < 5; j++) {
      int b = m * 20 + j;
      acc += (float)u[(size_t)b * SAMP + (size_t)c * HWP + t] * (1.0f / denom[b]);
    }
    accm[m] = acc;
  }
#pragma unroll
  for (int m = 0; m < 5; m++) {
    float v = accm[m];
#pragma unroll
    for (int off = 32; off; off >>= 1) v += __shfl_down(v, off, 64);
    accm[m] = v;
  }
  __shared__ float rs[4][5];
  if ((t & 63) == 0) {
#pragma unroll
    for (int m = 0; m < 5; m++) rs[wv][m] = accm[m];
  }
  __syncthreads();
  if (t < 5) sproto[t * 512 + c] =
      (rs[0][t] + rs[1][t] + rs[2][t] + rs[3][t]) * (1.0f / 1280.0f);
}

// ---- K4a: per (query n, gc-quad): partial dots + qq from u (fp16) ----
// half4 loads (8 B/lane, was 2-B scalar); thread = (gc-lane, position-quad).
// part layout [n][gc][6][256]; float4 stores.
__global__ __launch_bounds__(256) void k_part(const _Float16* __restrict__ u,
                                             const float* __restrict__ sproto,
                                             float* __restrict__ part) {
  __shared__ float s_l[5 * 256];       // [m][gcl*64 + c]
  int n = blockIdx.x >> 1, gq = blockIdx.x & 1;
  int b = (n / 15) * 20 + 5 + (n % 15);
  int t = threadIdx.x;
  int gcl = t >> 6;                    // 0..3 -> gc = gq*4 + gcl
  int gc  = gq * 4 + gcl;
  int pq  = (t & 63) << 2;             // position quad base
  for (int i = t; i < 1280; i += 256)
    s_l[i] = sproto[(i >> 8) * 512 + gq * 256 + (i & 255)];
  __syncthreads();
  const _Float16* ub = u + (size_t)b * SAMP + (size_t)gc * 64 * HWP + pq;
  float dot[5][4] = {}, qq[4] = {0, 0, 0, 0};
#pragma unroll 4
  for (int c = 0; c < 64; c++) {
    half4 v = *(const half4*)(ub + c * HWP);
    float sv[5];
#pragma unroll
    for (int m = 0; m < 5; m++) sv[m] = s_l[m * 256 + gcl * 64 + c];
#pragma unroll
    for (int k = 0; k < 4; k++) {
      float val = (float)v[k];
      qq[k] += val * val;
#pragma unroll
      for (int m = 0; m < 5; m++) dot[m][k] += val * sv[m];
    }
  }
  float* pp = part + (size_t)(n * 8 + gc) * 6 * 256 + pq;
#pragma unroll
  for (int m = 0; m < 5; m++) {
    float4 o; o.x = dot[m][0]; o.y = dot[m][1]; o.z = dot[m][2]; o.w = dot[m][3];
    *(float4*)(pp + m * 256) = o;
  }
  float4 oq; oq.x = qq[0]; oq.y = qq[1]; oq.z = qq[2]; oq.w = qq[3];
  *(float4*)(pp + 5 * 256) = oq;
}

// ---- K4b: combine partials -> cosine -> softmax(5) -> spatial mean ----
// Also computes pref[m] = 10/max(||s[m]||,eps) per block (folds former k_sn).
__global__ __launch_bounds__(256) void k_comb(const float* __restrict__ part,
                                             const float* __restrict__ sproto,
                                             float* __restrict__ out) {
  int n = blockIdx.x, t = threadIdx.x;   // t = position f
  int wv = t >> 6;
  // --- inline k_sn: redundant per block, 10 KB reads ---
  __shared__ float prefs[5];
  __shared__ float rsn[4][5];
  {
    float sn2[5];
#pragma unroll
    for (int m = 0; m < 5; m++) {
      float v1 = sproto[m * 512 + t], v2 = sproto[m * 512 + 256 + t];
      sn2[m] = v1 * v1 + v2 * v2;
    }
#pragma unroll
    for (int m = 0; m < 5; m++) {
      float v = sn2[m];
#pragma unroll
      for (int off = 32; off; off >>= 1) v += __shfl_down(v, off, 64);
      sn2[m] = v;
    }
    if ((t & 63) == 0) {
#pragma unroll
      for (int m = 0; m < 5; m++) rsn[wv][m] = sn2[m];
    }
    __syncthreads();
    if (t < 5) prefs[t] =
        10.0f / fmaxf(sqrtf(rsn[0][t] + rsn[1][t] + rsn[2][t] + rsn[3][t]), 1e-8f);
    __syncthreads();
  }
  float dot[5] = {0, 0, 0, 0, 0}, qq = 0.f;
#pragma unroll
  for (int gc = 0; gc < 8; gc++) {
    const float* pp = part + (size_t)(n * 8 + gc) * 6 * 256 + t;
    dot[0] += pp[0 * 256]; dot[1] += pp[1 * 256]; dot[2] += pp[2 * 256];
    dot[3] += pp[3 * 256]; dot[4] += pp[4 * 256]; qq += pp[5 * 256];
  }
  float iqn = 1.0f / fmaxf(sqrtf(qq), 1e-20f);
  float sc[5], mx = -1e30f;
#pragma unroll
  for (int m = 0; m < 5; m++) { sc[m] = dot[m] * prefs[m] * iqn; mx = fmaxf(mx, sc[m]); }
  float p[5], ssum = 0.f;
#pragma unroll
  for (int m = 0; m < 5; m++) { p[m] = __expf(sc[m] - mx); ssum += p[m]; }
  float rr = 1.0f / ssum;
#pragma unroll
  for (int m = 0; m < 5; m++) {
    float v = p[m] * rr;
#pragma unroll
    for (int off = 32; off; off >>= 1) v += __shfl_down(v, off, 64);
    p[m] = v;   // lane0 of each wave holds wave sum
  }
  __shared__ float rs[4][5];
  if ((t & 63) == 0) {
#pragma unroll
    for (int m = 0; m < 5; m++) rs[t >> 6][m] = p[m];
  }
  __syncthreads();
  if (t < 5) out[n * 5 + t] =
      (rs[0][t] + rs[1][t] + rs[2][t] + rs[3][t]) * (1.0f / 256.0f);
}

extern "C" void kernel_launch(void* const* d_in, const int* in_sizes, int n_in,
                              void* d_out, int out_size, void* d_ws, size_t ws_size,
                              hipStream_t stream) {
  const float* x    = (const float*)d_in[0];   // (100,512,16,16)
  const float* W    = (const float*)d_in[1];   // (512,512)
  const float* bias = (const float*)d_in[2];   // (512,)
  float* out = (float*)d_out;                  // (75,5) fp32

  char* ws = (char*)d_ws;
  _Float16* xh     = (_Float16*)(ws + 0);          // 26,214,400 B (dead after gemm)
  float*    part   = (float*)   (ws + 0);          //  3,686,400 B (aliases xh)
  _Float16* Wh     = (_Float16*)(ws + 26214400);   //    524,288 B
  _Float16* u      = (_Float16*)(ws + 26738688);   // 26,214,400 B  u = x*exp(logit)
  float*    denom  = (float*)   (ws + 52953088);   //        512 B
  float*    sproto = (float*)   (ws + 52953600);   //     10,240 B

  k_txpose <<<3456, 256, 0, stream>>>(x, xh, W, Wh, denom);  // + W-pack + denom zero
  k_gemm   <<<800,  256, 0, stream>>>(Wh, xh, bias, u, denom);
  k_proto  <<<512,  256, 0, stream>>>(u, denom, sproto);
  k_part   <<<150,  256, 0, stream>>>(u, sproto, part);
  k_comb   <<<75,   256, 0, stream>>>(part, sproto, out);
}

// Round 5
// 134.716 us; speedup vs baseline: 1.2554x; 1.2554x over previous
//
#include <hip/hip_runtime.h>
#include <hip/hip_bf16.h>
#include <math.h>

typedef _Float16 half8 __attribute__((ext_vector_type(8)));
typedef float f32x4 __attribute__((ext_vector_type(4)));

#define BATCH 100
#define CH    512
#define HWP   256
#define SAMP  (CH * HWP)   // 131072 elems per sample

// ---- async global->LDS 16B (wave-uniform LDS base + lane*16) ----
__device__ __forceinline__ void async16(const void* g, void* l) {
  __builtin_amdgcn_global_load_lds(
      (const __attribute__((address_space(1))) unsigned int*)g,
      (__attribute__((address_space(3))) unsigned int*)l, 16, 0, 0);
}

// ---- K0: transpose + fp32->fp16:  x[b][c][p] -> xh[b][p][c]
// 64c x 64p tile per block; LDS fp32 [64][69] (pad 5 -> max 2-way alias = free).
// Blocks >= 3200: W fp32->fp16 conversion; block 3200 also zeroes denom
// (replaces the hipMemsetAsync dispatch).
__global__ __launch_bounds__(256) void k_txpose(const float* __restrict__ x,
                                               _Float16* __restrict__ xh,
                                               const float* __restrict__ W,
                                               _Float16* __restrict__ Wh,
                                               float* __restrict__ denom) {
  __shared__ float tb[64][69];
  int bid  = blockIdx.x;
  if (bid >= 3200) {                 // W conversion tail: 256 blocks
    int base = (bid - 3200) * 1024 + threadIdx.x;
#pragma unroll
    for (int j = 0; j < 4; j++) Wh[base + j * 256] = (_Float16)W[base + j * 256];
    if (bid == 3200 && threadIdx.x < 128) denom[threadIdx.x] = 0.0f;
    return;
  }
  int b    = bid >> 5;          // 32 tiles per batch
  int tile = bid & 31;
  int c0 = (tile >> 2) << 6;    // 8 c-tiles of 64
  int p0 = (tile & 3) << 6;     // 4 p-tiles of 64
  int t = threadIdx.x;
  const float* xb = x + (size_t)b * SAMP;
#pragma unroll
  for (int it = 0; it < 4; it++) {
    int ch = it * 256 + t;
    int c  = ch >> 4;           // 0..63
    int pc = (ch & 15) << 2;    // 0..60
    float4 v = *(const float4*)(xb + (size_t)(c0 + c) * HWP + p0 + pc);
    tb[c][pc] = v.x; tb[c][pc + 1] = v.y; tb[c][pc + 2] = v.z; tb[c][pc + 3] = v.w;
  }
  __syncthreads();
  _Float16* xhb = xh + (size_t)b * SAMP;
#pragma unroll
  for (int it = 0; it < 2; it++) {
    int ch = it * 256 + t;
    int p  = ch >> 3;           // 0..63
    int ck = (ch & 7) << 3;     // 0..56
    half8 h;
#pragma unroll
    for (int j = 0; j < 8; j++) h[j] = (_Float16)tb[ck + j][p];
    *(half8*)(xhb + (size_t)(p0 + p) * CH + c0 + ck) = h;
  }
}

// ---- K1: batched GEMM + fused exp + denom partial + u = x*e (fp16) store.
// EXACT best-measured variant (round-1, <=41.4 us): runtime-q double-buffer
// (STAGE(next) before compute(cur), one barrier/step), unswizzled frag reads,
// bijective XCD swizzle, padded [128][136] epilogue tile, NO launch_bounds
// min-waves (round-4's (256,5) forced VGPR 48 -> 90 MB of accumulator spill).
__global__ __launch_bounds__(256) void k_gemm(const _Float16* __restrict__ Wh,
                                             const _Float16* __restrict__ xh,
                                             const float* __restrict__ bias,
                                             _Float16* __restrict__ u,
                                             float* __restrict__ denom) {
  // K-loop uses two 8192-half buffers (32 KiB); epilogue reuses all
  // 17408 halfs as padded x-tile [128p][136c] (pad 8 -> <=2-way bank alias).
  __shared__ __align__(16) _Float16 smem[128 * 136];
  int bid = blockIdx.x;
  // bijective XCD swizzle (800 % 8 == 0, 100 per XCD)
  int w     = (bid & 7) * 100 + (bid >> 3);
  int batch = w >> 3;
  int sub   = w & 7;
  int ot = sub & 3, pt = sub >> 2;     // o-tile fastest: 4 o-tiles share one x-tile in L2
  int o0 = ot * 128, p0 = pt * 128;
  const _Float16* Bg = xh + (size_t)batch * SAMP;   // [p][c] 256x512

  int t  = threadIdx.x;
  int wv = t >> 6, ln = t & 63;
  int qd = ln >> 4, r = ln & 15;
  int wm0 = (wv >> 1) * 64, wn0 = (wv & 1) * 64;

  auto stage = [&](int q, int kk) {
    _Float16* As = smem + q * 8192;   // 128x32
    _Float16* Bs = As + 4096;         // 128x32
#pragma unroll
    for (int it = 0; it < 2; it++) {
      int ch  = it * 256 + t;         // 0..511 chunks of 16B
      int row = ch >> 2;              // 0..127
      int qc  = ch & 3;               // 4 chunks per 64B row
      char* la = (char*)As + (size_t)(it * 256 + wv * 64) * 16;   // wave-uniform
      char* lb = (char*)Bs + (size_t)(it * 256 + wv * 64) * 16;
      async16((const char*)(Wh + (size_t)(o0 + row) * 512 + kk + qc * 8), la);
      async16((const char*)(Bg + (size_t)(p0 + row) * 512 + kk + qc * 8), lb);
    }
  };

  f32x4 acc[4][4] = {};
  stage(0, 0);
  __syncthreads();                    // vmcnt(0) drain of prologue stage

  for (int ks = 0; ks < 16; ks++) {
    int q = ks & 1;
    if (ks < 15) stage(q ^ 1, (ks + 1) * 32);   // prefetch next K-step
    const _Float16* As = smem + q * 8192;
    const _Float16* Bs = As + 4096;
    half8 af[4], bf[4];
#pragma unroll
    for (int i = 0; i < 4; i++)
      af[i] = *(const half8*)(As + (wm0 + i * 16 + r) * 32 + qd * 8);
#pragma unroll
    for (int j = 0; j < 4; j++)
      bf[j] = *(const half8*)(Bs + (wn0 + j * 16 + r) * 32 + qd * 8);
#pragma unroll
    for (int i = 0; i < 4; i++)
#pragma unroll
      for (int j = 0; j < 4; j++)
        acc[i][j] = __builtin_amdgcn_mfma_f32_16x16x32_f16(af[i], bf[j], acc[i][j], 0, 0, 0);
    __syncthreads();                  // one barrier/step: drains prefetch + frees cur buf
  }

  // ---- epilogue: restage x-tile (from xh, [p][c] fp16, c-contig) into padded LDS
#pragma unroll
  for (int it = 0; it < 8; it++) {
    int ch = it * 256 + t;        // 0..2047 half8-chunks
    int p  = ch >> 4;             // 0..127
    int ck = ch & 15;             // *8 halfs
    half8 v = *(const half8*)(Bg + (size_t)(p0 + p) * CH + o0 + ck * 8);
    *(half8*)(smem + p * 136 + ck * 8) = v;
  }
  __syncthreads();

  _Float16* outb = u + (size_t)batch * SAMP;    // [o][p]
  float lsum = 0.f;
#pragma unroll
  for (int i = 0; i < 4; i++) {
#pragma unroll
    for (int rg = 0; rg < 4; rg++) {
      int ol = wm0 + i * 16 + qd * 4 + rg;      // local o (== mask channel)
      float bv = bias[o0 + ol];
#pragma unroll
      for (int j = 0; j < 4; j++) {
        int pl = wn0 + j * 16 + r;              // local p
        float ev = __expf(acc[i][j][rg] + bv);
        lsum += ev;
        float xv = (float)smem[pl * 136 + ol];
        outb[(size_t)(o0 + ol) * HWP + p0 + pl] = (_Float16)(xv * ev);
      }
    }
  }
#pragma unroll
  for (int off = 32; off; off >>= 1) lsum += __shfl_down(lsum, off, 64);
  __shared__ float rs[4];
  if (ln == 0) rs[wv] = lsum;
  __syncthreads();
  if (t == 0) atomicAdd(&denom[batch], rs[0] + rs[1] + rs[2] + rs[3]);
}

// ---- K3: prototypes s[m][c] = (1/1280) * sum_j invd_j * sum_p u ----
// One block per channel c; 5 prototypes each.
__global__ __launch_bounds__(256) void k_proto(const _Float16* __restrict__ u,
                                              const float* __restrict__ denom,
                                              float* __restrict__ sproto) {
  int c = blockIdx.x;
  int t = threadIdx.x;                 // position p
  int wv = t >> 6;
  float accm[5];
#pragma unroll
  for (int m = 0; m < 5; m++) {
    float acc = 0.f;
#pragma unroll
    for (int j = 0; j < 5; j++) {
      int b = m * 20 + j;
      acc += (float)u[(size_t)b * SAMP + (size_t)c * HWP + t] * (1.0f / denom[b]);
    }
    accm[m] = acc;
  }
#pragma unroll
  for (int m = 0; m < 5; m++) {
    float v = accm[m];
#pragma unroll
    for (int off = 32; off; off >>= 1) v += __shfl_down(v, off, 64);
    accm[m] = v;
  }
  __shared__ float rs[4][5];
  if ((t & 63) == 0) {
#pragma unroll
    for (int m = 0; m < 5; m++) rs[wv][m] = accm[m];
  }
  __syncthreads();
  if (t < 5) sproto[t * 512 + c] =
      (rs[0][t] + rs[1][t] + rs[2][t] + rs[3][t]) * (1.0f / 1280.0f);
}

// ---- K4a: per (query n, c-chunk gc of 64): partial dots + qq from u (fp16) ----
// part layout [n][gc][6][256] -> fully coalesced stores/loads.
__global__ __launch_bounds__(256) void k_part(const _Float16* __restrict__ u,
                                             const float* __restrict__ sproto,
                                             float* __restrict__ part) {
  __shared__ float s_l[5 * 64];
  int n = blockIdx.x >> 3, gc = blockIdx.x & 7;
  int b = (n / 15) * 20 + 5 + (n % 15);
  int t = threadIdx.x;                // position f
  for (int i = t; i < 320; i += 256)  // 320 entries > 256 threads
    s_l[i] = sproto[(i >> 6) * 512 + gc * 64 + (i & 63)];
  __syncthreads();
  const _Float16* ub = u + (size_t)b * SAMP + (size_t)gc * 64 * HWP;
  float dot[5] = {0, 0, 0, 0, 0}, qq = 0.f;
#pragma unroll 8
  for (int c = 0; c < 64; c++) {
    float v = (float)ub[c * HWP + t];
    qq += v * v;
#pragma unroll
    for (int m = 0; m < 5; m++) dot[m] += v * s_l[m * 64 + c];
  }
  float* pp = part + (size_t)(n * 8 + gc) * 6 * 256 + t;
  pp[0 * 256] = dot[0]; pp[1 * 256] = dot[1]; pp[2 * 256] = dot[2];
  pp[3 * 256] = dot[3]; pp[4 * 256] = dot[4]; pp[5 * 256] = qq;
}

// ---- K4b: combine partials -> cosine -> softmax(5) -> spatial mean ----
// Also computes pref[m] = 10/max(||s[m]||,eps) inline (folds former k_sn).
__global__ __launch_bounds__(256) void k_comb(const float* __restrict__ part,
                                             const float* __restrict__ sproto,
                                             float* __restrict__ out) {
  int n = blockIdx.x, t = threadIdx.x;   // t = position f
  int wv = t >> 6;
  __shared__ float prefs[5];
  __shared__ float rsn[4][5];
  {
    float sn2[5];
#pragma unroll
    for (int m = 0; m < 5; m++) {
      float v1 = sproto[m * 512 + t], v2 = sproto[m * 512 + 256 + t];
      sn2[m] = v1 * v1 + v2 * v2;
    }
#pragma unroll
    for (int m = 0; m < 5; m++) {
      float v = sn2[m];
#pragma unroll
      for (int off = 32; off; off >>= 1) v += __shfl_down(v, off, 64);
      sn2[m] = v;
    }
    if ((t & 63) == 0) {
#pragma unroll
      for (int m = 0; m < 5; m++) rsn[wv][m] = sn2[m];
    }
    __syncthreads();
    if (t < 5) prefs[t] =
        10.0f / fmaxf(sqrtf(rsn[0][t] + rsn[1][t] + rsn[2][t] + rsn[3][t]), 1e-8f);
    __syncthreads();
  }
  float dot[5] = {0, 0, 0, 0, 0}, qq = 0.f;
#pragma unroll
  for (int gc = 0; gc < 8; gc++) {
    const float* pp = part + (size_t)(n * 8 + gc) * 6 * 256 + t;
    dot[0] += pp[0 * 256]; dot[1] += pp[1 * 256]; dot[2] += pp[2 * 256];
    dot[3] += pp[3 * 256]; dot[4] += pp[4 * 256]; qq += pp[5 * 256];
  }
  float iqn = 1.0f / fmaxf(sqrtf(qq), 1e-20f);
  float sc[5], mx = -1e30f;
#pragma unroll
  for (int m = 0; m < 5; m++) { sc[m] = dot[m] * prefs[m] * iqn; mx = fmaxf(mx, sc[m]); }
  float p[5], ssum = 0.f;
#pragma unroll
  for (int m = 0; m < 5; m++) { p[m] = __expf(sc[m] - mx); ssum += p[m]; }
  float rr = 1.0f / ssum;
#pragma unroll
  for (int m = 0; m < 5; m++) {
    float v = p[m] * rr;
#pragma unroll
    for (int off = 32; off; off >>= 1) v += __shfl_down(v, off, 64);
    p[m] = v;   // lane0 of each wave holds wave sum
  }
  __shared__ float rs[4][5];
  if ((t & 63) == 0) {
#pragma unroll
    for (int m = 0; m < 5; m++) rs[t >> 6][m] = p[m];
  }
  __syncthreads();
  if (t < 5) out[n * 5 + t] =
      (rs[0][t] + rs[1][t] + rs[2][t] + rs[3][t]) * (1.0f / 256.0f);
}

extern "C" void kernel_launch(void* const* d_in, const int* in_sizes, int n_in,
                              void* d_out, int out_size, void* d_ws, size_t ws_size,
                              hipStream_t stream) {
  const float* x    = (const float*)d_in[0];   // (100,512,16,16)
  const float* W    = (const float*)d_in[1];   // (512,512)
  const float* bias = (const float*)d_in[2];   // (512,)
  float* out = (float*)d_out;                  // (75,5) fp32

  char* ws = (char*)d_ws;
  _Float16* xh     = (_Float16*)(ws + 0);          // 26,214,400 B (dead after gemm)
  float*    part   = (float*)   (ws + 0);          //  2,764,800 B (aliases xh)
  _Float16* Wh     = (_Float16*)(ws + 26214400);   //    524,288 B
  _Float16* u      = (_Float16*)(ws + 26738688);   // 26,214,400 B  u = x*exp(logit)
  float*    denom  = (float*)   (ws + 52953088);   //        512 B
  float*    sproto = (float*)   (ws + 52953600);   //     10,240 B

  k_txpose <<<3456, 256, 0, stream>>>(x, xh, W, Wh, denom);  // + W-convert + denom zero
  k_gemm   <<<800,  256, 0, stream>>>(Wh, xh, bias, u, denom);
  k_proto  <<<512,  256, 0, stream>>>(u, denom, sproto);
  k_part   <<<600,  256, 0, stream>>>(u, sproto, part);
  k_comb   <<<75,   256, 0, stream>>>(part, sproto, out);
}

// Round 6
// 134.091 us; speedup vs baseline: 1.2612x; 1.0047x over previous
//
#include <hip/hip_runtime.h>
#include <hip/hip_bf16.h>
#include <math.h>

typedef _Float16 half8 __attribute__((ext_vector_type(8)));
typedef float f32x4 __attribute__((ext_vector_type(4)));

#define BATCH 100
#define CH    512
#define HWP   256
#define SAMP  (CH * HWP)   // 131072 elems per sample

// ---- async global->LDS 16B (wave-uniform LDS base + lane*16) ----
__device__ __forceinline__ void async16(const void* g, void* l) {
  __builtin_amdgcn_global_load_lds(
      (const __attribute__((address_space(1))) unsigned int*)g,
      (__attribute__((address_space(3))) unsigned int*)l, 16, 0, 0);
}

// ---- K0: transpose + fp32->fp16:  x[b][c][p] -> xh[b][p][c]
// 64c x 64p tile per block; LDS fp32 [64][69] (pad 5 -> max 2-way alias = free).
// Blocks >= 3200: W fp32->fp16 conversion; block 3200 also zeroes denom.
__global__ __launch_bounds__(256) void k_txpose(const float* __restrict__ x,
                                               _Float16* __restrict__ xh,
                                               const float* __restrict__ W,
                                               _Float16* __restrict__ Wh,
                                               float* __restrict__ denom) {
  __shared__ float tb[64][69];
  int bid  = blockIdx.x;
  if (bid >= 3200) {                 // W conversion tail: 256 blocks
    int base = (bid - 3200) * 1024 + threadIdx.x;
#pragma unroll
    for (int j = 0; j < 4; j++) Wh[base + j * 256] = (_Float16)W[base + j * 256];
    if (bid == 3200 && threadIdx.x < 128) denom[threadIdx.x] = 0.0f;
    return;
  }
  int b    = bid >> 5;          // 32 tiles per batch
  int tile = bid & 31;
  int c0 = (tile >> 2) << 6;    // 8 c-tiles of 64
  int p0 = (tile & 3) << 6;     // 4 p-tiles of 64
  int t = threadIdx.x;
  const float* xb = x + (size_t)b * SAMP;
#pragma unroll
  for (int it = 0; it < 4; it++) {
    int ch = it * 256 + t;
    int c  = ch >> 4;           // 0..63
    int pc = (ch & 15) << 2;    // 0..60
    float4 v = *(const float4*)(xb + (size_t)(c0 + c) * HWP + p0 + pc);
    tb[c][pc] = v.x; tb[c][pc + 1] = v.y; tb[c][pc + 2] = v.z; tb[c][pc + 3] = v.w;
  }
  __syncthreads();
  _Float16* xhb = xh + (size_t)b * SAMP;
#pragma unroll
  for (int it = 0; it < 2; it++) {
    int ch = it * 256 + t;
    int p  = ch >> 3;           // 0..63
    int ck = (ch & 7) << 3;     // 0..56
    half8 h;
#pragma unroll
    for (int j = 0; j < 8; j++) h[j] = (_Float16)tb[ck + j][p];
    *(half8*)(xhb + (size_t)(p0 + p) * CH + c0 + ck) = h;
  }
}

// ---- K1: batched GEMM + fused exp + denom partial + u = x*e (fp16) store.
// R5 structure + T4 COUNTED VMCNT: raw s_barrier + s_waitcnt vmcnt(4) so the
// prefetch DMA stays in flight ACROSS the barrier (old __syncthreads drained
// vmcnt(0) each step -> prefetch window = compute phase only, shorter than L2
// latency -> collective stall each of 16 steps). Two raw barriers per step:
//   B1 (after per-wave vmcnt(4)): buf q fully landed for all waves
//   B2 (after MFMA): all reads of buf q done before ks+1 issues overwrite
// vmcnt counting: stage() = exactly 4 global_load_lds per wave; at the wait
// point 8 are outstanding (4 old buf-q + 4 new buf-q^1) -> vmcnt(4) completes
// exactly the old 4. Never 0 mid-loop.
__global__ __launch_bounds__(256) void k_gemm(const _Float16* __restrict__ Wh,
                                             const _Float16* __restrict__ xh,
                                             const float* __restrict__ bias,
                                             _Float16* __restrict__ u,
                                             float* __restrict__ denom) {
  __shared__ __align__(16) _Float16 smem[128 * 136];
  int bid = blockIdx.x;
  // bijective XCD swizzle (800 % 8 == 0, 100 per XCD)
  int w     = (bid & 7) * 100 + (bid >> 3);
  int batch = w >> 3;
  int sub   = w & 7;
  int ot = sub & 3, pt = sub >> 2;     // o-tile fastest: 4 o-tiles share one x-tile in L2
  int o0 = ot * 128, p0 = pt * 128;
  const _Float16* Bg = xh + (size_t)batch * SAMP;   // [p][c] 256x512

  int t  = threadIdx.x;
  int wv = t >> 6, ln = t & 63;
  int qd = ln >> 4, r = ln & 15;
  int wm0 = (wv >> 1) * 64, wn0 = (wv & 1) * 64;

  auto stage = [&](int q, int kk) {
    _Float16* As = smem + q * 8192;   // 128x32
    _Float16* Bs = As + 4096;         // 128x32
#pragma unroll
    for (int it = 0; it < 2; it++) {
      int ch  = it * 256 + t;         // 0..511 chunks of 16B
      int row = ch >> 2;              // 0..127
      int qc  = ch & 3;               // 4 chunks per 64B row
      char* la = (char*)As + (size_t)(it * 256 + wv * 64) * 16;   // wave-uniform
      char* lb = (char*)Bs + (size_t)(it * 256 + wv * 64) * 16;
      async16((const char*)(Wh + (size_t)(o0 + row) * 512 + kk + qc * 8), la);
      async16((const char*)(Bg + (size_t)(p0 + row) * 512 + kk + qc * 8), lb);
    }
  };

  f32x4 acc[4][4] = {};
  stage(0, 0);                        // 4 loads in flight

  for (int ks = 0; ks < 16; ks++) {
    int q = ks & 1;
    if (ks < 15) {
      stage(q ^ 1, (ks + 1) * 32);    // prefetch next: 8 outstanding
      asm volatile("s_waitcnt vmcnt(4)" ::: "memory");   // oldest 4 (buf q) done
    } else {
      asm volatile("s_waitcnt vmcnt(0)" ::: "memory");
    }
    __builtin_amdgcn_s_barrier();     // B1: buf q ready for all waves
    asm volatile("" ::: "memory");
    const _Float16* As = smem + q * 8192;
    const _Float16* Bs = As + 4096;
    half8 af[4], bf[4];
#pragma unroll
    for (int i = 0; i < 4; i++)
      af[i] = *(const half8*)(As + (wm0 + i * 16 + r) * 32 + qd * 8);
#pragma unroll
    for (int j = 0; j < 4; j++)
      bf[j] = *(const half8*)(Bs + (wn0 + j * 16 + r) * 32 + qd * 8);
#pragma unroll
    for (int i = 0; i < 4; i++)
#pragma unroll
      for (int j = 0; j < 4; j++)
        acc[i][j] = __builtin_amdgcn_mfma_f32_16x16x32_f16(af[i], bf[j], acc[i][j], 0, 0, 0);
    asm volatile("" ::: "memory");
    __builtin_amdgcn_s_barrier();     // B2: reads of buf q done (overwritten at ks+1)
  }

  // ---- epilogue: restage x-tile (from xh, [p][c] fp16, c-contig) into padded LDS
#pragma unroll
  for (int it = 0; it < 8; it++) {
    int ch = it * 256 + t;        // 0..2047 half8-chunks
    int p  = ch >> 4;             // 0..127
    int ck = ch & 15;             // *8 halfs
    half8 v = *(const half8*)(Bg + (size_t)(p0 + p) * CH + o0 + ck * 8);
    *(half8*)(smem + p * 136 + ck * 8) = v;
  }
  __syncthreads();

  _Float16* outb = u + (size_t)batch * SAMP;    // [o][p]
  float lsum = 0.f;
#pragma unroll
  for (int i = 0; i < 4; i++) {
#pragma unroll
    for (int rg = 0; rg < 4; rg++) {
      int ol = wm0 + i * 16 + qd * 4 + rg;      // local o (== mask channel)
      float bv = bias[o0 + ol];
#pragma unroll
      for (int j = 0; j < 4; j++) {
        int pl = wn0 + j * 16 + r;              // local p
        float ev = __expf(acc[i][j][rg] + bv);
        lsum += ev;
        float xv = (float)smem[pl * 136 + ol];
        outb[(size_t)(o0 + ol) * HWP + p0 + pl] = (_Float16)(xv * ev);
      }
    }
  }
#pragma unroll
  for (int off = 32; off; off >>= 1) lsum += __shfl_down(lsum, off, 64);
  __shared__ float rs[4];
  if (ln == 0) rs[wv] = lsum;
  __syncthreads();
  if (t == 0) atomicAdd(&denom[batch], rs[0] + rs[1] + rs[2] + rs[3]);
}

// ---- K3: prototypes s[m][c] = (1/1280) * sum_j invd_j * sum_p u ----
__global__ __launch_bounds__(256) void k_proto(const _Float16* __restrict__ u,
                                              const float* __restrict__ denom,
                                              float* __restrict__ sproto) {
  int c = blockIdx.x;
  int t = threadIdx.x;                 // position p
  int wv = t >> 6;
  float accm[5];
#pragma unroll
  for (int m = 0; m < 5; m++) {
    float acc = 0.f;
#pragma unroll
    for (int j = 0; j < 5; j++) {
      int b = m * 20 + j;
      acc += (float)u[(size_t)b * SAMP + (size_t)c * HWP + t] * (1.0f / denom[b]);
    }
    accm[m] = acc;
  }
#pragma unroll
  for (int m = 0; m < 5; m++) {
    float v = accm[m];
#pragma unroll
    for (int off = 32; off; off >>= 1) v += __shfl_down(v, off, 64);
    accm[m] = v;
  }
  __shared__ float rs[4][5];
  if ((t & 63) == 0) {
#pragma unroll
    for (int m = 0; m < 5; m++) rs[wv][m] = accm[m];
  }
  __syncthreads();
  if (t < 5) sproto[t * 512 + c] =
      (rs[0][t] + rs[1][t] + rs[2][t] + rs[3][t]) * (1.0f / 1280.0f);
}

// ---- K4a: per (query n, c-chunk gc of 64): partial dots + qq from u (fp16) ----
// part layout [n][gc][6][256] -> fully coalesced stores/loads.
__global__ __launch_bounds__(256) void k_part(const _Float16* __restrict__ u,
                                             const float* __restrict__ sproto,
                                             float* __restrict__ part) {
  __shared__ float s_l[5 * 64];
  int n = blockIdx.x >> 3, gc = blockIdx.x & 7;
  int b = (n / 15) * 20 + 5 + (n % 15);
  int t = threadIdx.x;                // position f
  for (int i = t; i < 320; i += 256)  // 320 entries > 256 threads
    s_l[i] = sproto[(i >> 6) * 512 + gc * 64 + (i & 63)];
  __syncthreads();
  const _Float16* ub = u + (size_t)b * SAMP + (size_t)gc * 64 * HWP;
  float dot[5] = {0, 0, 0, 0, 0}, qq = 0.f;
#pragma unroll 8
  for (int c = 0; c < 64; c++) {
    float v = (float)ub[c * HWP + t];
    qq += v * v;
#pragma unroll
    for (int m = 0; m < 5; m++) dot[m] += v * s_l[m * 64 + c];
  }
  float* pp = part + (size_t)(n * 8 + gc) * 6 * 256 + t;
  pp[0 * 256] = dot[0]; pp[1 * 256] = dot[1]; pp[2 * 256] = dot[2];
  pp[3 * 256] = dot[3]; pp[4 * 256] = dot[4]; pp[5 * 256] = qq;
}

// ---- K4b: combine partials -> cosine -> softmax(5) -> spatial mean ----
// Also computes pref[m] = 10/max(||s[m]||,eps) inline (folds former k_sn).
__global__ __launch_bounds__(256) void k_comb(const float* __restrict__ part,
                                             const float* __restrict__ sproto,
                                             float* __restrict__ out) {
  int n = blockIdx.x, t = threadIdx.x;   // t = position f
  int wv = t >> 6;
  __shared__ float prefs[5];
  __shared__ float rsn[4][5];
  {
    float sn2[5];
#pragma unroll
    for (int m = 0; m < 5; m++) {
      float v1 = sproto[m * 512 + t], v2 = sproto[m * 512 + 256 + t];
      sn2[m] = v1 * v1 + v2 * v2;
    }
#pragma unroll
    for (int m = 0; m < 5; m++) {
      float v = sn2[m];
#pragma unroll
      for (int off = 32; off; off >>= 1) v += __shfl_down(v, off, 64);
      sn2[m] = v;
    }
    if ((t & 63) == 0) {
#pragma unroll
      for (int m = 0; m < 5; m++) rsn[wv][m] = sn2[m];
    }
    __syncthreads();
    if (t < 5) prefs[t] =
        10.0f / fmaxf(sqrtf(rsn[0][t] + rsn[1][t] + rsn[2][t] + rsn[3][t]), 1e-8f);
    __syncthreads();
  }
  float dot[5] = {0, 0, 0, 0, 0}, qq = 0.f;
#pragma unroll
  for (int gc = 0; gc < 8; gc++) {
    const float* pp = part + (size_t)(n * 8 + gc) * 6 * 256 + t;
    dot[0] += pp[0 * 256]; dot[1] += pp[1 * 256]; dot[2] += pp[2 * 256];
    dot[3] += pp[3 * 256]; dot[4] += pp[4 * 256]; qq += pp[5 * 256];
  }
  float iqn = 1.0f / fmaxf(sqrtf(qq), 1e-20f);
  float sc[5], mx = -1e30f;
#pragma unroll
  for (int m = 0; m < 5; m++) { sc[m] = dot[m] * prefs[m] * iqn; mx = fmaxf(mx, sc[m]); }
  float p[5], ssum = 0.f;
#pragma unroll
  for (int m = 0; m < 5; m++) { p[m] = __expf(sc[m] - mx); ssum += p[m]; }
  float rr = 1.0f / ssum;
#pragma unroll
  for (int m = 0; m < 5; m++) {
    float v = p[m] * rr;
#pragma unroll
    for (int off = 32; off; off >>= 1) v += __shfl_down(v, off, 64);
    p[m] = v;   // lane0 of each wave holds wave sum
  }
  __shared__ float rs[4][5];
  if ((t & 63) == 0) {
#pragma unroll
    for (int m = 0; m < 5; m++) rs[t >> 6][m] = p[m];
  }
  __syncthreads();
  if (t < 5) out[n * 5 + t] =
      (rs[0][t] + rs[1][t] + rs[2][t] + rs[3][t]) * (1.0f / 256.0f);
}

extern "C" void kernel_launch(void* const* d_in, const int* in_sizes, int n_in,
                              void* d_out, int out_size, void* d_ws, size_t ws_size,
                              hipStream_t stream) {
  const float* x    = (const float*)d_in[0];   // (100,512,16,16)
  const float* W    = (const float*)d_in[1];   // (512,512)
  const float* bias = (const float*)d_in[2];   // (512,)
  float* out = (float*)d_out;                  // (75,5) fp32

  char* ws = (char*)d_ws;
  _Float16* xh     = (_Float16*)(ws + 0);          // 26,214,400 B (dead after gemm)
  float*    part   = (float*)   (ws + 0);          //  2,764,800 B (aliases xh)
  _Float16* Wh     = (_Float16*)(ws + 26214400);   //    524,288 B
  _Float16* u      = (_Float16*)(ws + 26738688);   // 26,214,400 B  u = x*exp(logit)
  float*    denom  = (float*)   (ws + 52953088);   //        512 B
  float*    sproto = (float*)   (ws + 52953600);   //     10,240 B

  k_txpose <<<3456, 256, 0, stream>>>(x, xh, W, Wh, denom);  // + W-convert + denom zero
  k_gemm   <<<800,  256, 0, stream>>>(Wh, xh, bias, u, denom);
  k_proto  <<<512,  256, 0, stream>>>(u, denom, sproto);
  k_part   <<<600,  256, 0, stream>>>(u, sproto, part);
  k_comb   <<<75,   256, 0, stream>>>(part, sproto, out);
}